// Round 11
// baseline (203.334 us; speedup 1.0000x reference)
//
#include <hip/hip_runtime.h>
#include <hip/hip_bf16.h>
#include <math.h>

#define NTOT   64000
#define NSEG   16
#define SEGSZ  4000
#define KNN    40
#define FIN    16
#define NPROP  64
#define FOUT   128
#define NIN    144   // FIN + 2*NPROP

typedef unsigned short u16;
typedef __attribute__((ext_vector_type(8))) short bf16x8;   // 8 bf16 = 4 VGPR
typedef __attribute__((ext_vector_type(4))) float f32x4;

__device__ __forceinline__ u16 f2bf(float f)
{
    __hip_bfloat16 h = __float2bfloat16(f);   // round-to-nearest
    return *reinterpret_cast<u16*>(&h);
}

// ---------------- workspace layout (bytes) ----------------
// coords : [64000] float4               @ 0          (1,024,000)
// nn     : [64000] f32 (|c|^2)          @ 1,024,000  (256,000)
// feat   : [64000][64] f32 row-major    @ 1,280,000  (16,384,000)
// featB  : [64000][144] bf16 row-major  @ 17,664,000 (18,432,000)
//          (x | max | mean) -- k1 writes x, k2 writes max/mean; k4's A.

// ---------------- K1: coords + |c|^2 + feat + featB.x ----------------
__global__ __launch_bounds__(256)
void k1_proj(const float* __restrict__ x,
             const float* __restrict__ Ws, const float* __restrict__ bs,
             const float* __restrict__ Wf, const float* __restrict__ bf,
             float4* __restrict__ coords, float* __restrict__ nn,
             float* __restrict__ feat, u16* __restrict__ featB)
{
    __shared__ float sWs[FIN * 4];
    __shared__ float sbs[4];
    __shared__ float sWf[FIN * NPROP];
    __shared__ float sbf[NPROP];
    int t = threadIdx.x;
    if (t < FIN * 4) sWs[t] = Ws[t];
    if (t < 4) sbs[t] = bs[t];
    for (int i = t; i < FIN * NPROP; i += 256) sWf[i] = Wf[i];
    if (t < NPROP) sbf[t] = bf[t];
    __syncthreads();

    int q = blockIdx.x * 256 + t;   // grid is exactly 250*256 = 64000
    const float4* xv = (const float4*)(x + q * FIN);
    float4 x0 = xv[0], x1 = xv[1], x2 = xv[2], x3 = xv[3];
    float xr[FIN] = {x0.x, x0.y, x0.z, x0.w, x1.x, x1.y, x1.z, x1.w,
                     x2.x, x2.y, x2.z, x2.w, x3.x, x3.y, x3.z, x3.w};

    float c0 = sbs[0], c1 = sbs[1], c2 = sbs[2], c3 = sbs[3];
#pragma unroll
    for (int k = 0; k < FIN; k++) {
        float xk = xr[k];
        c0 += xk * sWs[k * 4 + 0];
        c1 += xk * sWs[k * 4 + 1];
        c2 += xk * sWs[k * 4 + 2];
        c3 += xk * sWs[k * 4 + 3];
    }
    coords[q] = make_float4(c0, c1, c2, c3);
    nn[q] = c0 * c0 + c1 * c1 + c2 * c2 + c3 * c3;

    // x block of featB row, bf16 packed (2 x uint4 = 16 bf16)
    unsigned int xp[8];
#pragma unroll
    for (int i = 0; i < 8; i++)
        xp[i] = (unsigned int)f2bf(xr[2 * i]) |
                ((unsigned int)f2bf(xr[2 * i + 1]) << 16);
    uint4* fb = (uint4*)(featB + (size_t)q * NIN);
    fb[0] = make_uint4(xp[0], xp[1], xp[2], xp[3]);
    fb[1] = make_uint4(xp[4], xp[5], xp[6], xp[7]);

#pragma unroll
    for (int f0 = 0; f0 < NPROP; f0 += 4) {
        float a0 = sbf[f0], a1 = sbf[f0 + 1], a2 = sbf[f0 + 2], a3 = sbf[f0 + 3];
#pragma unroll
        for (int k = 0; k < FIN; k++) {
            float xk = xr[k];
            const float* w = &sWf[k * NPROP + f0];
            a0 += xk * w[0]; a1 += xk * w[1]; a2 += xk * w[2]; a3 += xk * w[3];
        }
        *(float4*)(feat + q * NPROP + f0) = make_float4(a0, a1, a2, a3);
    }
}

// ---------------- K2 (fused): kNN select + aggregate, 2 queries/wave ----------------
// Identical selection to round 10 (proven): dot-trick distance clamped >= 0,
// key = (s_bits & 0xFFFFF000) | j, per-lane sorted top-4, batch4 bitonic
// partial-merge, exact-41st full-key binary search, self excluded by INDEX
// bits, ballot+mbcnt compaction into wave-private LDS.
// Only change: collected outputs stored as bf16 into featB (k4's MFMA A).
#define K2_WPB 4
#define QPW    2

__device__ __forceinline__ void ce(unsigned int& a, unsigned int& b)
{
    unsigned int lo = min(a, b);
    unsigned int hi = max(a, b);
    a = lo; b = hi;
}

__device__ __forceinline__ void batch4(unsigned int (&arr)[4],
                                       unsigned int k0, unsigned int k1,
                                       unsigned int k2, unsigned int k3)
{
    ce(k0, k1); ce(k2, k3); ce(k0, k2); ce(k1, k3); ce(k1, k2);
    arr[0] = min(arr[0], k3);
    arr[1] = min(arr[1], k2);
    arr[2] = min(arr[2], k1);
    arr[3] = min(arr[3], k0);
    ce(arr[0], arr[2]); ce(arr[1], arr[3]); ce(arr[0], arr[1]); ce(arr[2], arr[3]);
}

__global__ __launch_bounds__(256)
void k2_knn_agg(const float4* __restrict__ coords, const float* __restrict__ nn,
                const float* __restrict__ feat, u16* __restrict__ featB)
{
    __shared__ unsigned int win[K2_WPB][QPW][KNN];
    int lane = threadIdx.x & 63;
    int wave = threadIdx.x >> 6;
    int qA = (blockIdx.x * K2_WPB + wave) * QPW;   // grid 8000 -> 64000 queries
    int seg = qA / SEGSZ;
    int segbase = seg * SEGSZ;
    int lqA = qA - segbase;                        // lqB = lqA + 1
    float4 qcA = coords[qA];
    float4 qcB = coords[qA + 1];
    const float4* cbase = coords + segbase;
    const float* nbase = nn + segbase;

    float sqqA = qcA.x * qcA.x + qcA.y * qcA.y + qcA.z * qcA.z + qcA.w * qcA.w;
    float sqqB = qcB.x * qcB.x + qcB.y * qcB.y + qcB.z * qcB.z + qcB.w * qcB.w;
    float mAx = -2.f * qcA.x, mAy = -2.f * qcA.y, mAz = -2.f * qcA.z, mAw = -2.f * qcA.w;
    float mBx = -2.f * qcB.x, mBy = -2.f * qcB.y, mBz = -2.f * qcB.z, mBw = -2.f * qcB.w;

    unsigned int arrA[4], arrB[4];
#pragma unroll
    for (int n = 0; n < 4; n++) { arrA[n] = 0xFFFFFFFFu; arrB[n] = 0xFFFFFFFFu; }

#define DKEY(cc, njs, j, mx, my, mz, mw) \
    ((__float_as_uint(fmaxf(fmaf((cc).x, (mx), fmaf((cc).y, (my), \
      fmaf((cc).z, (mz), fmaf((cc).w, (mw), (njs))))), 0.f)) & 0xFFFFF000u) \
     | (unsigned int)(j))

    for (int b = 0; b < 15; b++) {
        int j0 = b * 256 + lane;
        float4 c0 = cbase[j0];
        float4 c1 = cbase[j0 + 64];
        float4 c2 = cbase[j0 + 128];
        float4 c3 = cbase[j0 + 192];
        float n0 = nbase[j0], n1 = nbase[j0 + 64];
        float n2 = nbase[j0 + 128], n3 = nbase[j0 + 192];
        unsigned int a0 = DKEY(c0, n0 + sqqA, j0,       mAx, mAy, mAz, mAw);
        unsigned int a1 = DKEY(c1, n1 + sqqA, j0 + 64,  mAx, mAy, mAz, mAw);
        unsigned int a2 = DKEY(c2, n2 + sqqA, j0 + 128, mAx, mAy, mAz, mAw);
        unsigned int a3 = DKEY(c3, n3 + sqqA, j0 + 192, mAx, mAy, mAz, mAw);
        batch4(arrA, a0, a1, a2, a3);
        unsigned int b0 = DKEY(c0, n0 + sqqB, j0,       mBx, mBy, mBz, mBw);
        unsigned int b1 = DKEY(c1, n1 + sqqB, j0 + 64,  mBx, mBy, mBz, mBw);
        unsigned int b2 = DKEY(c2, n2 + sqqB, j0 + 128, mBx, mBy, mBz, mBw);
        unsigned int b3 = DKEY(c3, n3 + sqqB, j0 + 192, mBx, mBy, mBz, mBw);
        batch4(arrB, b0, b1, b2, b3);
    }
    {
        int j0 = 3840 + lane;
        float4 c0 = cbase[j0];
        float4 c1 = cbase[j0 + 64];
        float n0 = nbase[j0], n1 = nbase[j0 + 64];
        int j2 = j0 + 128;
        int j2c = (j2 < SEGSZ) ? j2 : (SEGSZ - 1);
        float4 c2 = cbase[j2c];
        float n2 = nbase[j2c];
        unsigned int a0 = DKEY(c0, n0 + sqqA, j0,      mAx, mAy, mAz, mAw);
        unsigned int a1 = DKEY(c1, n1 + sqqA, j0 + 64, mAx, mAy, mAz, mAw);
        unsigned int a2 = (j2 < SEGSZ)
            ? (unsigned int)DKEY(c2, n2 + sqqA, j2, mAx, mAy, mAz, mAw)
            : 0xFFFFFFFFu;
        batch4(arrA, a0, a1, a2, 0xFFFFFFFFu);
        unsigned int b0 = DKEY(c0, n0 + sqqB, j0,      mBx, mBy, mBz, mBw);
        unsigned int b1 = DKEY(c1, n1 + sqqB, j0 + 64, mBx, mBy, mBz, mBw);
        unsigned int b2 = (j2 < SEGSZ)
            ? (unsigned int)DKEY(c2, n2 + sqqB, j2, mBx, mBy, mBz, mBw)
            : 0xFFFFFFFFu;
        batch4(arrB, b0, b1, b2, 0xFFFFFFFFu);
    }
#undef DKEY

    const float* fseg = feat + segbase * NPROP + lane;

#define SELECT_AND_AGG(ARR, LQ, Q, SLOT)                                      \
    {                                                                         \
        unsigned int klo = 0u, khi = 0xFFFFFFFFu;                             \
        for (int it = 0; it < 32; it++) {                                     \
            unsigned int mid = klo + ((khi - klo) >> 1);                      \
            int c = 0;                                                        \
            c += __popcll(__ballot(ARR[0] <= mid));                           \
            c += __popcll(__ballot(ARR[1] <= mid));                           \
            c += __popcll(__ballot(ARR[2] <= mid));                           \
            c += __popcll(__ballot(ARR[3] <= mid));                           \
            if (c >= KNN + 1) khi = mid; else klo = mid + 1;                  \
        }                                                                     \
        unsigned int K41 = khi;                                               \
        int base = 0;                                                         \
        _Pragma("unroll")                                                     \
        for (int n = 0; n < 4; n++) {                                         \
            bool qual = (ARR[n] <= K41) &&                                    \
                        ((ARR[n] & 0xFFFu) != (unsigned int)(LQ));            \
            unsigned long long m = __ballot(qual);                            \
            int pos = base + __builtin_amdgcn_mbcnt_hi((unsigned int)(m >> 32),\
                            __builtin_amdgcn_mbcnt_lo((unsigned int)m, 0));   \
            if (qual && pos < KNN) win[wave][SLOT][pos] = ARR[n];             \
            base += __popcll(m);                                              \
            if (base >= KNN) break;                                           \
        }                                                                     \
        float mxv = -INFINITY, smv = 0.f;                                     \
        _Pragma("unroll 4")                                                   \
        for (int k = 0; k < KNN; k++) {                                       \
            unsigned int key = win[wave][SLOT][k];                            \
            float d2 = __uint_as_float(key & 0xFFFFF000u);                    \
            int nl = (int)(key & 0xFFFu);                                     \
            float w = __expf(-(d2 * 10.f + 1e-5f));                           \
            float f = fseg[nl * NPROP];                                       \
            float wf = w * f;                                                 \
            mxv = fmaxf(mxv, wf);                                             \
            smv += wf;                                                        \
        }                                                                     \
        featB[(size_t)(Q) * NIN + FIN + lane]         = f2bf(mxv);            \
        featB[(size_t)(Q) * NIN + FIN + NPROP + lane] = f2bf(smv * (1.f/KNN));\
    }

    SELECT_AND_AGG(arrA, lqA,     qA,     0)
    SELECT_AND_AGG(arrB, lqA + 1, qA + 1, 1)
#undef SELECT_AND_AGG
}

// ---------------- K4: out = tanh(featB @ Wo + bo), bf16 MFMA ----------------
// A = featB [64000][144] bf16 (direct per-lane 16B fragment loads).
// B = Wo staged TRANSPOSED in LDS as bf16 BsT[col][k], stride 168 (pad ->
// ~2-way banks), zero-padded k in [144,160) so the K=160 sweep is exact.
// A's k>=144 fragment reads spill into the next row's data: finite bf16
// garbage x B=0 = 0, so harmless (never NaN/Inf: poison 0xAAAA is finite).
// mfma_f32_16x16x32_bf16 layouts (m89-verified family): A row=lane&15,
// k=8*(lane>>4)+e; B col=lane&15, same k; D col=lane&15, row=4*(lane>>4)+r.
// Wave = 16-row strip x 128 cols: 5 K-chunks x 8 col-tiles = 40 MFMA.
__global__ __launch_bounds__(256)
void k4_gemm(const u16* __restrict__ featB, const float* __restrict__ Wo,
             const float* __restrict__ bo, float* __restrict__ out)
{
    __shared__ u16 BsT[128 * 168];   // 43008 B

    int t = threadIdx.x;
    // stage Wo^T as bf16 pairs: (k, k+1) packed per dword, zeros for k >= 144
    for (int idx = t; idx < 80 * 128; idx += 256) {
        int kp = idx >> 7;           // k-pair 0..79 -> k = 2kp
        int col = idx & 127;
        int k0 = kp * 2;
        float w0 = (k0 < NIN)     ? Wo[k0 * FOUT + col]       : 0.f;
        float w1 = (k0 + 1 < NIN) ? Wo[(k0 + 1) * FOUT + col] : 0.f;
        unsigned int pk = (unsigned int)f2bf(w0) | ((unsigned int)f2bf(w1) << 16);
        *(unsigned int*)&BsT[col * 168 + k0] = pk;
    }
    __syncthreads();

    int lane = t & 63;
    int wave = t >> 6;
    int R = blockIdx.x * 64 + wave * 16;    // grid 1000 -> 64000 rows
    int rc = lane & 15;                      // A-row within strip == B/D col
    int koff = lane >> 4;                    // k-block 0..3

    f32x4 acc[8];
#pragma unroll
    for (int c = 0; c < 8; c++) acc[c] = (f32x4){0.f, 0.f, 0.f, 0.f};

    const u16* arow = featB + (size_t)(R + rc) * NIN + koff * 8;
#pragma unroll
    for (int kc = 0; kc < 5; kc++) {
        bf16x8 af = *(const bf16x8*)(arow + kc * 32);
#pragma unroll
        for (int c = 0; c < 8; c++) {
            const u16* bp = &BsT[(c * 16 + rc) * 168 + kc * 32 + koff * 8];
            bf16x8 bfr = *(const bf16x8*)bp;
            acc[c] = __builtin_amdgcn_mfma_f32_16x16x32_bf16(af, bfr, acc[c], 0, 0, 0);
        }
    }

    // epilogue: bias + tanh(z) = 1 - 2/(e^{2z}+1); D row = R + 4*koff + r
    int orow = R + koff * 4;
#pragma unroll
    for (int c = 0; c < 8; c++) {
        int col = c * 16 + rc;
        float b = bo[col];
#pragma unroll
        for (int r = 0; r < 4; r++) {
            float z = acc[c][r] + b;
            float e = __expf(2.f * z);
            out[(size_t)(orow + r) * FOUT + col] = 1.f - 2.f / (e + 1.f);
        }
    }
}

extern "C" void kernel_launch(void* const* d_in, const int* in_sizes, int n_in,
                              void* d_out, int out_size, void* d_ws, size_t ws_size,
                              hipStream_t stream)
{
    const float* x  = (const float*)d_in[0];
    const float* Ws = (const float*)d_in[2];
    const float* bs = (const float*)d_in[3];
    const float* Wf = (const float*)d_in[4];
    const float* bf = (const float*)d_in[5];
    const float* Wo = (const float*)d_in[6];
    const float* bo = (const float*)d_in[7];
    float* out = (float*)d_out;

    char* ws = (char*)d_ws;
    float4* coords = (float4*)(ws);
    float*  nn     = (float*)(ws + 1024000);
    float*  feat   = (float*)(ws + 1280000);
    u16*    featB  = (u16*)(ws + 17664000);

    hipLaunchKernelGGL(k1_proj,    dim3(250),  dim3(256), 0, stream,
                       x, Ws, bs, Wf, bf, coords, nn, feat, featB);
    hipLaunchKernelGGL(k2_knn_agg, dim3(8000), dim3(256), 0, stream,
                       coords, nn, feat, featB);
    hipLaunchKernelGGL(k4_gemm,    dim3(1000), dim3(256), 0, stream,
                       featB, Wo, bo, out);
}

// Round 12
// 189.248 us; speedup vs baseline: 1.0744x; 1.0744x over previous
//
#include <hip/hip_runtime.h>
#include <hip/hip_bf16.h>
#include <math.h>

#define NTOT   64000
#define NSEG   16
#define SEGSZ  4000
#define KNN    40
#define FIN    16
#define NPROP  64
#define FOUT   128
#define NIN    144   // FIN + 2*NPROP

typedef unsigned short u16;
typedef __attribute__((ext_vector_type(8))) short bf16x8;   // 8 bf16 = 4 VGPR
typedef __attribute__((ext_vector_type(4))) float f32x4;

__device__ __forceinline__ u16 f2bf(float f)
{
    __hip_bfloat16 h = __float2bfloat16(f);   // round-to-nearest
    return *reinterpret_cast<u16*>(&h);
}

// ---------------- workspace layout (bytes) ----------------
// coords : [64000] float4               @ 0          (1,024,000)
// nn     : [64000] f32 (|c|^2)          @ 1,024,000  (256,000)
// feat   : [64000][64] f32 row-major    @ 1,280,000  (16,384,000)
// featB  : [64000][144] bf16 row-major  @ 17,664,000 (18,432,000)

// ---------------- K1: coords + |c|^2 + feat + featB.x ----------------
__global__ __launch_bounds__(256)
void k1_proj(const float* __restrict__ x,
             const float* __restrict__ Ws, const float* __restrict__ bs,
             const float* __restrict__ Wf, const float* __restrict__ bf,
             float4* __restrict__ coords, float* __restrict__ nn,
             float* __restrict__ feat, u16* __restrict__ featB)
{
    __shared__ float sWs[FIN * 4];
    __shared__ float sbs[4];
    __shared__ float sWf[FIN * NPROP];
    __shared__ float sbf[NPROP];
    int t = threadIdx.x;
    if (t < FIN * 4) sWs[t] = Ws[t];
    if (t < 4) sbs[t] = bs[t];
    for (int i = t; i < FIN * NPROP; i += 256) sWf[i] = Wf[i];
    if (t < NPROP) sbf[t] = bf[t];
    __syncthreads();

    int q = blockIdx.x * 256 + t;   // grid is exactly 250*256 = 64000
    const float4* xv = (const float4*)(x + q * FIN);
    float4 x0 = xv[0], x1 = xv[1], x2 = xv[2], x3 = xv[3];
    float xr[FIN] = {x0.x, x0.y, x0.z, x0.w, x1.x, x1.y, x1.z, x1.w,
                     x2.x, x2.y, x2.z, x2.w, x3.x, x3.y, x3.z, x3.w};

    float c0 = sbs[0], c1 = sbs[1], c2 = sbs[2], c3 = sbs[3];
#pragma unroll
    for (int k = 0; k < FIN; k++) {
        float xk = xr[k];
        c0 += xk * sWs[k * 4 + 0];
        c1 += xk * sWs[k * 4 + 1];
        c2 += xk * sWs[k * 4 + 2];
        c3 += xk * sWs[k * 4 + 3];
    }
    coords[q] = make_float4(c0, c1, c2, c3);
    nn[q] = c0 * c0 + c1 * c1 + c2 * c2 + c3 * c3;

    unsigned int xp[8];
#pragma unroll
    for (int i = 0; i < 8; i++)
        xp[i] = (unsigned int)f2bf(xr[2 * i]) |
                ((unsigned int)f2bf(xr[2 * i + 1]) << 16);
    uint4* fb = (uint4*)(featB + (size_t)q * NIN);
    fb[0] = make_uint4(xp[0], xp[1], xp[2], xp[3]);
    fb[1] = make_uint4(xp[4], xp[5], xp[6], xp[7]);

#pragma unroll
    for (int f0 = 0; f0 < NPROP; f0 += 4) {
        float a0 = sbf[f0], a1 = sbf[f0 + 1], a2 = sbf[f0 + 2], a3 = sbf[f0 + 3];
#pragma unroll
        for (int k = 0; k < FIN; k++) {
            float xk = xr[k];
            const float* w = &sWf[k * NPROP + f0];
            a0 += xk * w[0]; a1 += xk * w[1]; a2 += xk * w[2]; a3 += xk * w[3];
        }
        *(float4*)(feat + q * NPROP + f0) = make_float4(a0, a1, a2, a3);
    }
}

// ---------------- K2 (fused): kNN select + aggregate, 2 queries/wave ----------------
// Byte-identical to round 11 (proven: absmax 0.00851): dot-trick distance
// clamped >= 0, key = (s_bits & 0xFFFFF000) | j, per-lane sorted top-4,
// batch4 bitonic partial-merge, exact-41st full-key binary search, self
// excluded by INDEX bits, ballot+mbcnt compaction, lane=feature aggregation,
// bf16 outputs into featB.
#define K2_WPB 4
#define QPW    2

__device__ __forceinline__ void ce(unsigned int& a, unsigned int& b)
{
    unsigned int lo = min(a, b);
    unsigned int hi = max(a, b);
    a = lo; b = hi;
}

__device__ __forceinline__ void batch4(unsigned int (&arr)[4],
                                       unsigned int k0, unsigned int k1,
                                       unsigned int k2, unsigned int k3)
{
    ce(k0, k1); ce(k2, k3); ce(k0, k2); ce(k1, k3); ce(k1, k2);
    arr[0] = min(arr[0], k3);
    arr[1] = min(arr[1], k2);
    arr[2] = min(arr[2], k1);
    arr[3] = min(arr[3], k0);
    ce(arr[0], arr[2]); ce(arr[1], arr[3]); ce(arr[0], arr[1]); ce(arr[2], arr[3]);
}

__global__ __launch_bounds__(256)
void k2_knn_agg(const float4* __restrict__ coords, const float* __restrict__ nn,
                const float* __restrict__ feat, u16* __restrict__ featB)
{
    __shared__ unsigned int win[K2_WPB][QPW][KNN];
    int lane = threadIdx.x & 63;
    int wave = threadIdx.x >> 6;
    int qA = (blockIdx.x * K2_WPB + wave) * QPW;   // grid 8000 -> 64000 queries
    int seg = qA / SEGSZ;
    int segbase = seg * SEGSZ;
    int lqA = qA - segbase;                        // lqB = lqA + 1
    float4 qcA = coords[qA];
    float4 qcB = coords[qA + 1];
    const float4* cbase = coords + segbase;
    const float* nbase = nn + segbase;

    float sqqA = qcA.x * qcA.x + qcA.y * qcA.y + qcA.z * qcA.z + qcA.w * qcA.w;
    float sqqB = qcB.x * qcB.x + qcB.y * qcB.y + qcB.z * qcB.z + qcB.w * qcB.w;
    float mAx = -2.f * qcA.x, mAy = -2.f * qcA.y, mAz = -2.f * qcA.z, mAw = -2.f * qcA.w;
    float mBx = -2.f * qcB.x, mBy = -2.f * qcB.y, mBz = -2.f * qcB.z, mBw = -2.f * qcB.w;

    unsigned int arrA[4], arrB[4];
#pragma unroll
    for (int n = 0; n < 4; n++) { arrA[n] = 0xFFFFFFFFu; arrB[n] = 0xFFFFFFFFu; }

#define DKEY(cc, njs, j, mx, my, mz, mw) \
    ((__float_as_uint(fmaxf(fmaf((cc).x, (mx), fmaf((cc).y, (my), \
      fmaf((cc).z, (mz), fmaf((cc).w, (mw), (njs))))), 0.f)) & 0xFFFFF000u) \
     | (unsigned int)(j))

    for (int b = 0; b < 15; b++) {
        int j0 = b * 256 + lane;
        float4 c0 = cbase[j0];
        float4 c1 = cbase[j0 + 64];
        float4 c2 = cbase[j0 + 128];
        float4 c3 = cbase[j0 + 192];
        float n0 = nbase[j0], n1 = nbase[j0 + 64];
        float n2 = nbase[j0 + 128], n3 = nbase[j0 + 192];
        unsigned int a0 = DKEY(c0, n0 + sqqA, j0,       mAx, mAy, mAz, mAw);
        unsigned int a1 = DKEY(c1, n1 + sqqA, j0 + 64,  mAx, mAy, mAz, mAw);
        unsigned int a2 = DKEY(c2, n2 + sqqA, j0 + 128, mAx, mAy, mAz, mAw);
        unsigned int a3 = DKEY(c3, n3 + sqqA, j0 + 192, mAx, mAy, mAz, mAw);
        batch4(arrA, a0, a1, a2, a3);
        unsigned int b0 = DKEY(c0, n0 + sqqB, j0,       mBx, mBy, mBz, mBw);
        unsigned int b1 = DKEY(c1, n1 + sqqB, j0 + 64,  mBx, mBy, mBz, mBw);
        unsigned int b2 = DKEY(c2, n2 + sqqB, j0 + 128, mBx, mBy, mBz, mBw);
        unsigned int b3 = DKEY(c3, n3 + sqqB, j0 + 192, mBx, mBy, mBz, mBw);
        batch4(arrB, b0, b1, b2, b3);
    }
    {
        int j0 = 3840 + lane;
        float4 c0 = cbase[j0];
        float4 c1 = cbase[j0 + 64];
        float n0 = nbase[j0], n1 = nbase[j0 + 64];
        int j2 = j0 + 128;
        int j2c = (j2 < SEGSZ) ? j2 : (SEGSZ - 1);
        float4 c2 = cbase[j2c];
        float n2 = nbase[j2c];
        unsigned int a0 = DKEY(c0, n0 + sqqA, j0,      mAx, mAy, mAz, mAw);
        unsigned int a1 = DKEY(c1, n1 + sqqA, j0 + 64, mAx, mAy, mAz, mAw);
        unsigned int a2 = (j2 < SEGSZ)
            ? (unsigned int)DKEY(c2, n2 + sqqA, j2, mAx, mAy, mAz, mAw)
            : 0xFFFFFFFFu;
        batch4(arrA, a0, a1, a2, 0xFFFFFFFFu);
        unsigned int b0 = DKEY(c0, n0 + sqqB, j0,      mBx, mBy, mBz, mBw);
        unsigned int b1 = DKEY(c1, n1 + sqqB, j0 + 64, mBx, mBy, mBz, mBw);
        unsigned int b2 = (j2 < SEGSZ)
            ? (unsigned int)DKEY(c2, n2 + sqqB, j2, mBx, mBy, mBz, mBw)
            : 0xFFFFFFFFu;
        batch4(arrB, b0, b1, b2, 0xFFFFFFFFu);
    }
#undef DKEY

    const float* fseg = feat + segbase * NPROP + lane;

#define SELECT_AND_AGG(ARR, LQ, Q, SLOT)                                      \
    {                                                                         \
        unsigned int klo = 0u, khi = 0xFFFFFFFFu;                             \
        for (int it = 0; it < 32; it++) {                                     \
            unsigned int mid = klo + ((khi - klo) >> 1);                      \
            int c = 0;                                                        \
            c += __popcll(__ballot(ARR[0] <= mid));                           \
            c += __popcll(__ballot(ARR[1] <= mid));                           \
            c += __popcll(__ballot(ARR[2] <= mid));                           \
            c += __popcll(__ballot(ARR[3] <= mid));                           \
            if (c >= KNN + 1) khi = mid; else klo = mid + 1;                  \
        }                                                                     \
        unsigned int K41 = khi;                                               \
        int base = 0;                                                         \
        _Pragma("unroll")                                                     \
        for (int n = 0; n < 4; n++) {                                         \
            bool qual = (ARR[n] <= K41) &&                                    \
                        ((ARR[n] & 0xFFFu) != (unsigned int)(LQ));            \
            unsigned long long m = __ballot(qual);                            \
            int pos = base + __builtin_amdgcn_mbcnt_hi((unsigned int)(m >> 32),\
                            __builtin_amdgcn_mbcnt_lo((unsigned int)m, 0));   \
            if (qual && pos < KNN) win[wave][SLOT][pos] = ARR[n];             \
            base += __popcll(m);                                              \
            if (base >= KNN) break;                                           \
        }                                                                     \
        float mxv = -INFINITY, smv = 0.f;                                     \
        _Pragma("unroll 4")                                                   \
        for (int k = 0; k < KNN; k++) {                                       \
            unsigned int key = win[wave][SLOT][k];                            \
            float d2 = __uint_as_float(key & 0xFFFFF000u);                    \
            int nl = (int)(key & 0xFFFu);                                     \
            float w = __expf(-(d2 * 10.f + 1e-5f));                           \
            float f = fseg[nl * NPROP];                                       \
            float wf = w * f;                                                 \
            mxv = fmaxf(mxv, wf);                                             \
            smv += wf;                                                        \
        }                                                                     \
        featB[(size_t)(Q) * NIN + FIN + lane]         = f2bf(mxv);            \
        featB[(size_t)(Q) * NIN + FIN + NPROP + lane] = f2bf(smv * (1.f/KNN));\
    }

    SELECT_AND_AGG(arrA, lqA,     qA,     0)
    SELECT_AND_AGG(arrB, lqA + 1, qA + 1, 1)
#undef SELECT_AND_AGG
}

// ---------------- K4: out = tanh(featB @ Wo + bo), bf16 MFMA ----------------
// Round-12 change: grid 250 (256 rows/block, 4 strips of 16 per wave) --
// amortizes the 43 KB Wo^T LDS staging 4x vs round 11 (staging:compute byte
// ratio was 4:1 at grid 1000; kernel was staging-bound). Strip-0 A fragments
// prefetched into registers BEFORE the barrier (compiler cannot hoist loads
// across __syncthreads); bias loads hoisted (col is strip-invariant).
// MFMA sequence per strip identical to round 11 -> bit-identical output.
// Layouts (m89-verified): A row=lane&15, k=8*(lane>>4)+e; B col=lane&15,
// same k; D col=lane&15, row=4*(lane>>4)+r. BsT[col][k] stride 168 bf16;
// k in [144,160) zero-padded (A spill-reads x B=0 = 0, poison is finite).
__global__ __launch_bounds__(256)
void k4_gemm(const u16* __restrict__ featB, const float* __restrict__ Wo,
             const float* __restrict__ bo, float* __restrict__ out)
{
    __shared__ u16 BsT[128 * 168];   // 43008 B

    int t = threadIdx.x;
    for (int idx = t; idx < 80 * 128; idx += 256) {
        int kp = idx >> 7;           // k-pair 0..79 -> k = 2kp
        int col = idx & 127;
        int k0 = kp * 2;
        float w0 = (k0 < NIN)     ? Wo[k0 * FOUT + col]       : 0.f;
        float w1 = (k0 + 1 < NIN) ? Wo[(k0 + 1) * FOUT + col] : 0.f;
        unsigned int pk = (unsigned int)f2bf(w0) | ((unsigned int)f2bf(w1) << 16);
        *(unsigned int*)&BsT[col * 168 + k0] = pk;
    }

    int lane = t & 63;
    int wave = t >> 6;
    int rc = lane & 15;                      // A-row within strip == B/D col
    int koff = lane >> 4;                    // k-block 0..3
    int Rb = blockIdx.x * 256 + wave * 64;   // wave rows [Rb, Rb+64)

    // prefetch strip 0 A fragments before the barrier
    const u16* arow0 = featB + (size_t)(Rb + rc) * NIN + koff * 8;
    bf16x8 af0[5];
#pragma unroll
    for (int kc = 0; kc < 5; kc++) af0[kc] = *(const bf16x8*)(arow0 + kc * 32);

    // bias per col (strip-invariant)
    float bias[8];
#pragma unroll
    for (int c = 0; c < 8; c++) bias[c] = bo[c * 16 + rc];

    __syncthreads();

#pragma unroll
    for (int st = 0; st < 4; st++) {
        int R = Rb + st * 16;
        f32x4 acc[8];
#pragma unroll
        for (int c = 0; c < 8; c++) acc[c] = (f32x4){0.f, 0.f, 0.f, 0.f};

        const u16* arow = featB + (size_t)(R + rc) * NIN + koff * 8;
#pragma unroll
        for (int kc = 0; kc < 5; kc++) {
            bf16x8 af = (st == 0) ? af0[kc] : *(const bf16x8*)(arow + kc * 32);
#pragma unroll
            for (int c = 0; c < 8; c++) {
                const u16* bp = &BsT[(c * 16 + rc) * 168 + kc * 32 + koff * 8];
                bf16x8 bfr = *(const bf16x8*)bp;
                acc[c] = __builtin_amdgcn_mfma_f32_16x16x32_bf16(af, bfr, acc[c], 0, 0, 0);
            }
        }

        int orow = R + koff * 4;
#pragma unroll
        for (int c = 0; c < 8; c++) {
            int col = c * 16 + rc;
#pragma unroll
            for (int r = 0; r < 4; r++) {
                float z = acc[c][r] + bias[c];
                float e = __expf(2.f * z);
                out[(size_t)(orow + r) * FOUT + col] = 1.f - 2.f / (e + 1.f);
            }
        }
    }
}

extern "C" void kernel_launch(void* const* d_in, const int* in_sizes, int n_in,
                              void* d_out, int out_size, void* d_ws, size_t ws_size,
                              hipStream_t stream)
{
    const float* x  = (const float*)d_in[0];
    const float* Ws = (const float*)d_in[2];
    const float* bs = (const float*)d_in[3];
    const float* Wf = (const float*)d_in[4];
    const float* bf = (const float*)d_in[5];
    const float* Wo = (const float*)d_in[6];
    const float* bo = (const float*)d_in[7];
    float* out = (float*)d_out;

    char* ws = (char*)d_ws;
    float4* coords = (float4*)(ws);
    float*  nn     = (float*)(ws + 1024000);
    float*  feat   = (float*)(ws + 1280000);
    u16*    featB  = (u16*)(ws + 17664000);

    hipLaunchKernelGGL(k1_proj,    dim3(250),  dim3(256), 0, stream,
                       x, Ws, bs, Wf, bf, coords, nn, feat, featB);
    hipLaunchKernelGGL(k2_knn_agg, dim3(8000), dim3(256), 0, stream,
                       coords, nn, feat, featB);
    hipLaunchKernelGGL(k4_gemm,    dim3(250),  dim3(256), 0, stream,
                       featB, Wo, bo, out);
}

// Round 14
// 171.047 us; speedup vs baseline: 1.1888x; 1.1064x over previous
//
#include <hip/hip_runtime.h>
#include <hip/hip_bf16.h>
#include <math.h>

#define NTOT   64000
#define NSEG   16
#define SEGSZ  4000
#define KNN    40
#define FIN    16
#define NPROP  64
#define FOUT   128
#define NIN    144   // FIN + 2*NPROP

typedef unsigned short u16;
typedef __attribute__((ext_vector_type(8))) short bf16x8;   // 8 bf16 = 4 VGPR
typedef __attribute__((ext_vector_type(4))) float f32x4;

__device__ __forceinline__ u16 f2bf(float f)
{
    __hip_bfloat16 h = __float2bfloat16(f);   // round-to-nearest
    return *reinterpret_cast<u16*>(&h);
}

// ---------------- workspace layout (bytes) ----------------
// coords : [64000] float4               @ 0          (1,024,000)
// nn     : [64000] f32 (|c|^2)          @ 1,024,000  (256,000)
// feat   : [64000][64] f32 row-major    @ 1,280,000  (16,384,000)
// featB  : [64000][144] bf16 row-major  @ 17,664,000 (18,432,000)
// WoT    : [128][168] bf16 (k4 LDS img) @ 36,096,000 (43,008)

// ---------------- K1: coords + |c|^2 + feat + featB.x (+ Wo->bf16 prep) ----------------
__global__ __launch_bounds__(256)
void k1_proj(const float* __restrict__ x,
             const float* __restrict__ Ws, const float* __restrict__ bs,
             const float* __restrict__ Wf, const float* __restrict__ bf,
             const float* __restrict__ Wo,
             float4* __restrict__ coords, float* __restrict__ nn,
             float* __restrict__ feat, u16* __restrict__ featB,
             unsigned int* __restrict__ WoT32)
{
    __shared__ float sWs[FIN * 4];
    __shared__ float sbs[4];
    __shared__ float sWf[FIN * NPROP];
    __shared__ float sbf[NPROP];
    int t = threadIdx.x;
    if (t < FIN * 4) sWs[t] = Ws[t];
    if (t < 4) sbs[t] = bs[t];
    for (int i = t; i < FIN * NPROP; i += 256) sWf[i] = Wf[i];
    if (t < NPROP) sbf[t] = bf[t];

    // Wo -> WoT bf16 prep (exact image of k4's BsT): first 42 blocks,
    // idx = kp*128 + col (coalesced Wo reads); 10752 = 84 kpairs x 128 cols.
    if (blockIdx.x < 42) {
        int idx = blockIdx.x * 256 + t;        // 0..10751
        int kp  = idx >> 7;                    // k-pair 0..83
        int col = idx & 127;
        int k0  = kp * 2;
        float w0 = (k0 < NIN)     ? Wo[k0 * FOUT + col]       : 0.f;
        float w1 = (k0 + 1 < NIN) ? Wo[(k0 + 1) * FOUT + col] : 0.f;
        WoT32[col * 84 + kp] =
            (unsigned int)f2bf(w0) | ((unsigned int)f2bf(w1) << 16);
    }
    __syncthreads();

    int q = blockIdx.x * 256 + t;   // grid is exactly 250*256 = 64000
    const float4* xv = (const float4*)(x + q * FIN);
    float4 x0 = xv[0], x1 = xv[1], x2 = xv[2], x3 = xv[3];
    float xr[FIN] = {x0.x, x0.y, x0.z, x0.w, x1.x, x1.y, x1.z, x1.w,
                     x2.x, x2.y, x2.z, x2.w, x3.x, x3.y, x3.z, x3.w};

    float c0 = sbs[0], c1 = sbs[1], c2 = sbs[2], c3 = sbs[3];
#pragma unroll
    for (int k = 0; k < FIN; k++) {
        float xk = xr[k];
        c0 += xk * sWs[k * 4 + 0];
        c1 += xk * sWs[k * 4 + 1];
        c2 += xk * sWs[k * 4 + 2];
        c3 += xk * sWs[k * 4 + 3];
    }
    coords[q] = make_float4(c0, c1, c2, c3);
    nn[q] = c0 * c0 + c1 * c1 + c2 * c2 + c3 * c3;

    unsigned int xp[8];
#pragma unroll
    for (int i = 0; i < 8; i++)
        xp[i] = (unsigned int)f2bf(xr[2 * i]) |
                ((unsigned int)f2bf(xr[2 * i + 1]) << 16);
    uint4* fb = (uint4*)(featB + (size_t)q * NIN);
    fb[0] = make_uint4(xp[0], xp[1], xp[2], xp[3]);
    fb[1] = make_uint4(xp[4], xp[5], xp[6], xp[7]);

#pragma unroll
    for (int f0 = 0; f0 < NPROP; f0 += 4) {
        float a0 = sbf[f0], a1 = sbf[f0 + 1], a2 = sbf[f0 + 2], a3 = sbf[f0 + 3];
#pragma unroll
        for (int k = 0; k < FIN; k++) {
            float xk = xr[k];
            const float* w = &sWf[k * NPROP + f0];
            a0 += xk * w[0]; a1 += xk * w[1]; a2 += xk * w[2]; a3 += xk * w[3];
        }
        *(float4*)(feat + q * NPROP + f0) = make_float4(a0, a1, a2, a3);
    }
}

// ---------------- K2 (fused): kNN select + aggregate, 2 queries/wave ----------------
// Selection byte-identical to rounds 10-12 (proven). Round-13 change: the
// two queries' aggregation loops are INTERLEAVED (select A, select B, then
// one fused k-loop touching win[0][k] and win[1][k]) -> 2 independent
// gather+exp chains per iteration, double the MLP to hide LDS/L2 latency.
// Per-query op sequence unchanged -> bit-identical output.
#define K2_WPB 4
#define QPW    2

__device__ __forceinline__ void ce(unsigned int& a, unsigned int& b)
{
    unsigned int lo = min(a, b);
    unsigned int hi = max(a, b);
    a = lo; b = hi;
}

__device__ __forceinline__ void batch4(unsigned int (&arr)[4],
                                       unsigned int k0, unsigned int k1,
                                       unsigned int k2, unsigned int k3)
{
    ce(k0, k1); ce(k2, k3); ce(k0, k2); ce(k1, k3); ce(k1, k2);
    arr[0] = min(arr[0], k3);
    arr[1] = min(arr[1], k2);
    arr[2] = min(arr[2], k1);
    arr[3] = min(arr[3], k0);
    ce(arr[0], arr[2]); ce(arr[1], arr[3]); ce(arr[0], arr[1]); ce(arr[2], arr[3]);
}

__global__ __launch_bounds__(256)
void k2_knn_agg(const float4* __restrict__ coords, const float* __restrict__ nn,
                const float* __restrict__ feat, u16* __restrict__ featB)
{
    __shared__ unsigned int win[K2_WPB][QPW][KNN];
    int lane = threadIdx.x & 63;
    int wave = threadIdx.x >> 6;
    int qA = (blockIdx.x * K2_WPB + wave) * QPW;   // grid 8000 -> 64000 queries
    int seg = qA / SEGSZ;
    int segbase = seg * SEGSZ;
    int lqA = qA - segbase;                        // lqB = lqA + 1
    float4 qcA = coords[qA];
    float4 qcB = coords[qA + 1];
    const float4* cbase = coords + segbase;
    const float* nbase = nn + segbase;

    float sqqA = qcA.x * qcA.x + qcA.y * qcA.y + qcA.z * qcA.z + qcA.w * qcA.w;
    float sqqB = qcB.x * qcB.x + qcB.y * qcB.y + qcB.z * qcB.z + qcB.w * qcB.w;
    float mAx = -2.f * qcA.x, mAy = -2.f * qcA.y, mAz = -2.f * qcA.z, mAw = -2.f * qcA.w;
    float mBx = -2.f * qcB.x, mBy = -2.f * qcB.y, mBz = -2.f * qcB.z, mBw = -2.f * qcB.w;

    unsigned int arrA[4], arrB[4];
#pragma unroll
    for (int n = 0; n < 4; n++) { arrA[n] = 0xFFFFFFFFu; arrB[n] = 0xFFFFFFFFu; }

#define DKEY(cc, njs, j, mx, my, mz, mw) \
    ((__float_as_uint(fmaxf(fmaf((cc).x, (mx), fmaf((cc).y, (my), \
      fmaf((cc).z, (mz), fmaf((cc).w, (mw), (njs))))), 0.f)) & 0xFFFFF000u) \
     | (unsigned int)(j))

    for (int b = 0; b < 15; b++) {
        int j0 = b * 256 + lane;
        float4 c0 = cbase[j0];
        float4 c1 = cbase[j0 + 64];
        float4 c2 = cbase[j0 + 128];
        float4 c3 = cbase[j0 + 192];
        float n0 = nbase[j0], n1 = nbase[j0 + 64];
        float n2 = nbase[j0 + 128], n3 = nbase[j0 + 192];
        unsigned int a0 = DKEY(c0, n0 + sqqA, j0,       mAx, mAy, mAz, mAw);
        unsigned int a1 = DKEY(c1, n1 + sqqA, j0 + 64,  mAx, mAy, mAz, mAw);
        unsigned int a2 = DKEY(c2, n2 + sqqA, j0 + 128, mAx, mAy, mAz, mAw);
        unsigned int a3 = DKEY(c3, n3 + sqqA, j0 + 192, mAx, mAy, mAz, mAw);
        batch4(arrA, a0, a1, a2, a3);
        unsigned int b0 = DKEY(c0, n0 + sqqB, j0,       mBx, mBy, mBz, mBw);
        unsigned int b1 = DKEY(c1, n1 + sqqB, j0 + 64,  mBx, mBy, mBz, mBw);
        unsigned int b2 = DKEY(c2, n2 + sqqB, j0 + 128, mBx, mBy, mBz, mBw);
        unsigned int b3 = DKEY(c3, n3 + sqqB, j0 + 192, mBx, mBy, mBz, mBw);
        batch4(arrB, b0, b1, b2, b3);
    }
    {
        int j0 = 3840 + lane;
        float4 c0 = cbase[j0];
        float4 c1 = cbase[j0 + 64];
        float n0 = nbase[j0], n1 = nbase[j0 + 64];
        int j2 = j0 + 128;
        int j2c = (j2 < SEGSZ) ? j2 : (SEGSZ - 1);
        float4 c2 = cbase[j2c];
        float n2 = nbase[j2c];
        unsigned int a0 = DKEY(c0, n0 + sqqA, j0,      mAx, mAy, mAz, mAw);
        unsigned int a1 = DKEY(c1, n1 + sqqA, j0 + 64, mAx, mAy, mAz, mAw);
        unsigned int a2 = (j2 < SEGSZ)
            ? (unsigned int)DKEY(c2, n2 + sqqA, j2, mAx, mAy, mAz, mAw)
            : 0xFFFFFFFFu;
        batch4(arrA, a0, a1, a2, 0xFFFFFFFFu);
        unsigned int b0 = DKEY(c0, n0 + sqqB, j0,      mBx, mBy, mBz, mBw);
        unsigned int b1 = DKEY(c1, n1 + sqqB, j0 + 64, mBx, mBy, mBz, mBw);
        unsigned int b2 = (j2 < SEGSZ)
            ? (unsigned int)DKEY(c2, n2 + sqqB, j2, mBx, mBy, mBz, mBw)
            : 0xFFFFFFFFu;
        batch4(arrB, b0, b1, b2, 0xFFFFFFFFu);
    }
#undef DKEY

    // per-query: exact-41st binary search + compact into wave-private LDS.
#define SELECT(ARR, LQ, SLOT)                                                 \
    {                                                                         \
        unsigned int klo = 0u, khi = 0xFFFFFFFFu;                             \
        for (int it = 0; it < 32; it++) {                                     \
            unsigned int mid = klo + ((khi - klo) >> 1);                      \
            int c = 0;                                                        \
            c += __popcll(__ballot(ARR[0] <= mid));                           \
            c += __popcll(__ballot(ARR[1] <= mid));                           \
            c += __popcll(__ballot(ARR[2] <= mid));                           \
            c += __popcll(__ballot(ARR[3] <= mid));                           \
            if (c >= KNN + 1) khi = mid; else klo = mid + 1;                  \
        }                                                                     \
        unsigned int K41 = khi;                                               \
        int base = 0;                                                         \
        _Pragma("unroll")                                                     \
        for (int n = 0; n < 4; n++) {                                         \
            bool qual = (ARR[n] <= K41) &&                                    \
                        ((ARR[n] & 0xFFFu) != (unsigned int)(LQ));            \
            unsigned long long m = __ballot(qual);                            \
            int pos = base + __builtin_amdgcn_mbcnt_hi((unsigned int)(m >> 32),\
                            __builtin_amdgcn_mbcnt_lo((unsigned int)m, 0));   \
            if (qual && pos < KNN) win[wave][SLOT][pos] = ARR[n];             \
            base += __popcll(m);                                              \
            if (base >= KNN) break;                                           \
        }                                                                     \
    }

    SELECT(arrA, lqA,     0)
    SELECT(arrB, lqA + 1, 1)
#undef SELECT

    // fused aggregation: lane = feature; A and B interleaved (2 independent
    // gather+exp chains/iter); per-query accumulation order unchanged.
    const float* fseg = feat + segbase * NPROP + lane;
    float mxA = -INFINITY, smA = 0.f;
    float mxB = -INFINITY, smB = 0.f;
#pragma unroll 4
    for (int k = 0; k < KNN; k++) {
        unsigned int keyA = win[wave][0][k];
        unsigned int keyB = win[wave][1][k];
        int nlA = (int)(keyA & 0xFFFu);
        int nlB = (int)(keyB & 0xFFFu);
        float fA = fseg[nlA * NPROP];
        float fB = fseg[nlB * NPROP];
        float d2A = __uint_as_float(keyA & 0xFFFFF000u);
        float d2B = __uint_as_float(keyB & 0xFFFFF000u);
        float wA = __expf(-(d2A * 10.f + 1e-5f));
        float wB = __expf(-(d2B * 10.f + 1e-5f));
        float wfA = wA * fA;
        float wfB = wB * fB;
        mxA = fmaxf(mxA, wfA); smA += wfA;
        mxB = fmaxf(mxB, wfB); smB += wfB;
    }
    featB[(size_t)qA * NIN + FIN + lane]               = f2bf(mxA);
    featB[(size_t)qA * NIN + FIN + NPROP + lane]       = f2bf(smA * (1.f / KNN));
    featB[(size_t)(qA + 1) * NIN + FIN + lane]         = f2bf(mxB);
    featB[(size_t)(qA + 1) * NIN + FIN + NPROP + lane] = f2bf(smB * (1.f / KNN));
}

// ---------------- K4: out = tanh(featB @ Wo + bo), bf16 MFMA ----------------
// Wo^T arrives pre-converted (WoT, exact BsT image) -> staging is an
// 11-iteration uint4 memcpy (22 inst/thread vs ~320 with inline conversion).
// BsT bits, MFMA sequence, epilogue identical to round 12 -> bit-identical
// output. Grid 250: 256 rows/block, 4 strips/wave.
__global__ __launch_bounds__(256)
void k4_gemm(const u16* __restrict__ featB, const uint4* __restrict__ WoT,
             const float* __restrict__ bo, float* __restrict__ out)
{
    __shared__ u16 BsT[128 * 168];   // 43008 B

    int t = threadIdx.x;
    uint4* wdst = (uint4*)BsT;
#pragma unroll
    for (int it = 0; it < 11; it++) {
        int idx = it * 256 + t;
        if (idx < 2688) wdst[idx] = WoT[idx];
    }

    int lane = t & 63;
    int wave = t >> 6;
    int rc = lane & 15;                      // A-row within strip == B/D col
    int koff = lane >> 4;                    // k-block 0..3
    int Rb = blockIdx.x * 256 + wave * 64;   // wave rows [Rb, Rb+64)

    // prefetch strip 0 A fragments before the barrier
    const u16* arow0 = featB + (size_t)(Rb + rc) * NIN + koff * 8;
    bf16x8 af0[5];
#pragma unroll
    for (int kc = 0; kc < 5; kc++) af0[kc] = *(const bf16x8*)(arow0 + kc * 32);

    float bias[8];
#pragma unroll
    for (int c = 0; c < 8; c++) bias[c] = bo[c * 16 + rc];

    __syncthreads();

#pragma unroll
    for (int st = 0; st < 4; st++) {
        int R = Rb + st * 16;
        f32x4 acc[8];
#pragma unroll
        for (int c = 0; c < 8; c++) acc[c] = (f32x4){0.f, 0.f, 0.f, 0.f};

        const u16* arow = featB + (size_t)(R + rc) * NIN + koff * 8;
#pragma unroll
        for (int kc = 0; kc < 5; kc++) {
            bf16x8 af = (st == 0) ? af0[kc] : *(const bf16x8*)(arow + kc * 32);
#pragma unroll
            for (int c = 0; c < 8; c++) {
                const u16* bp = &BsT[(c * 16 + rc) * 168 + kc * 32 + koff * 8];
                bf16x8 bfr = *(const bf16x8*)bp;
                acc[c] = __builtin_amdgcn_mfma_f32_16x16x32_bf16(af, bfr, acc[c], 0, 0, 0);
            }
        }

        int orow = R + koff * 4;
#pragma unroll
        for (int c = 0; c < 8; c++) {
            int col = c * 16 + rc;
#pragma unroll
            for (int r = 0; r < 4; r++) {
                float z = acc[c][r] + bias[c];
                float e = __expf(2.f * z);
                out[(size_t)(orow + r) * FOUT + col] = 1.f - 2.f / (e + 1.f);
            }
        }
    }
}

extern "C" void kernel_launch(void* const* d_in, const int* in_sizes, int n_in,
                              void* d_out, int out_size, void* d_ws, size_t ws_size,
                              hipStream_t stream)
{
    const float* x  = (const float*)d_in[0];
    const float* Ws = (const float*)d_in[2];
    const float* bs = (const float*)d_in[3];
    const float* Wf = (const float*)d_in[4];
    const float* bf = (const float*)d_in[5];
    const float* Wo = (const float*)d_in[6];
    const float* bo = (const float*)d_in[7];
    float* out = (float*)d_out;

    char* ws = (char*)d_ws;
    float4*       coords = (float4*)(ws);
    float*        nn     = (float*)(ws + 1024000);
    float*        feat   = (float*)(ws + 1280000);
    u16*          featB  = (u16*)(ws + 17664000);
    unsigned int* WoT32  = (unsigned int*)(ws + 36096000);

    hipLaunchKernelGGL(k1_proj,    dim3(250),  dim3(256), 0, stream,
                       x, Ws, bs, Wf, bf, Wo, coords, nn, feat, featB, WoT32);
    hipLaunchKernelGGL(k2_knn_agg, dim3(8000), dim3(256), 0, stream,
                       coords, nn, feat, featB);
    hipLaunchKernelGGL(k4_gemm,    dim3(250),  dim3(256), 0, stream,
                       featB, (const uint4*)WoT32, bo, out);
}